// Round 5
// baseline (2599.506 us; speedup 1.0000x reference)
//
#include <hip/hip_runtime.h>

#define NN 10000
#define NE 200000
#define LDIM 128
#define PADB 136   // bf16 elements per LDS row (128 + 8)
#define NSTEP 10
#define LN_EPS 1e-5f

typedef unsigned short ushort_t;
typedef __attribute__((ext_vector_type(8))) short short8;
typedef __attribute__((ext_vector_type(4))) float f32x4;

#define MFMA16(a, b, c) __builtin_amdgcn_mfma_f32_16x16x32_bf16(a, b, c, 0, 0, 0)

__device__ __forceinline__ ushort_t f2bf(float f) {
  unsigned int u = __float_as_uint(f);
  return (ushort_t)((u + 0x7FFFu + ((u >> 16) & 1u)) >> 16);
}
__device__ __forceinline__ float bf2f(ushort_t h) {
  return __uint_as_float(((unsigned int)h) << 16);
}

// ---- shared-macro context: kernels declare t, lr, kg, rw, Abuf, Wbuf, acc ----

#define STAGE_WT(WT, KTOT, K0)                                              \
  {                                                                         \
    const ushort_t* src_ = (WT) + (size_t)(t >> 1) * (KTOT) + (K0) + (t & 1) * 64; \
    ushort_t* dst_ = &Wbuf[(t >> 1) * PADB + (t & 1) * 64];                 \
    _Pragma("unroll")                                                       \
    for (int q_ = 0; q_ < 8; ++q_)                                          \
      *(uint4*)(dst_ + q_ * 8) = *(const uint4*)(src_ + q_ * 8);            \
  }

#define INIT_ACC(BG)                                                        \
  _Pragma("unroll")                                                         \
  for (int nt_ = 0; nt_ < 8; ++nt_) {                                       \
    float bv_ = (BG)[nt_ * 16 + lr];                                        \
    acc[0][nt_] = (f32x4){bv_, bv_, bv_, bv_};                              \
    acc[1][nt_] = acc[0][nt_];                                              \
  }

// A from LDS (wave-private rows), B from LDS Wbuf (legacy path, needs barriers)
#define MFMA_K128()                                                         \
  _Pragma("unroll")                                                         \
  for (int ks_ = 0; ks_ < 4; ++ks_) {                                       \
    short8 a0_ = *(const short8*)&Abuf[(rw + lr) * PADB + ks_ * 32 + kg * 8];        \
    short8 a1_ = *(const short8*)&Abuf[(rw + 16 + lr) * PADB + ks_ * 32 + kg * 8];   \
    _Pragma("unroll")                                                       \
    for (int nt_ = 0; nt_ < 8; ++nt_) {                                     \
      short8 b_ = *(const short8*)&Wbuf[(nt_ * 16 + lr) * PADB + ks_ * 32 + kg * 8]; \
      acc[0][nt_] = MFMA16(a0_, b_, acc[0][nt_]);                           \
      acc[1][nt_] = MFMA16(a1_, b_, acc[1][nt_]);                           \
    }                                                                       \
  }

// A from LDS (wave-private rows), B direct from global (L2 broadcast) - no barrier
#define MFMA_K128_GW(WT, KTOT, KOFF)                                        \
  _Pragma("unroll")                                                         \
  for (int ks_ = 0; ks_ < 4; ++ks_) {                                       \
    short8 a0_ = *(const short8*)&Abuf[(rw + lr) * PADB + ks_ * 32 + kg * 8];        \
    short8 a1_ = *(const short8*)&Abuf[(rw + 16 + lr) * PADB + ks_ * 32 + kg * 8];   \
    _Pragma("unroll")                                                       \
    for (int nt_ = 0; nt_ < 8; ++nt_) {                                     \
      short8 b_ = *(const short8*)&(WT)[(size_t)(nt_ * 16 + lr) * (KTOT) + (KOFF) + ks_ * 32 + kg * 8]; \
      acc[0][nt_] = MFMA16(a0_, b_, acc[0][nt_]);                           \
      acc[1][nt_] = MFMA16(a1_, b_, acc[1][nt_]);                           \
    }                                                                       \
  }

// A gathered per-lane from global rows, B direct from global - no LDS, no barrier
#define MFMA_K128_GAW(A0P, A1P, WT, KTOT, KOFF)                             \
  _Pragma("unroll")                                                         \
  for (int ks_ = 0; ks_ < 4; ++ks_) {                                       \
    short8 a0_ = *(const short8*)&(A0P)[ks_ * 32 + kg * 8];                 \
    short8 a1_ = *(const short8*)&(A1P)[ks_ * 32 + kg * 8];                 \
    _Pragma("unroll")                                                       \
    for (int nt_ = 0; nt_ < 8; ++nt_) {                                     \
      short8 b_ = *(const short8*)&(WT)[(size_t)(nt_ * 16 + lr) * (KTOT) + (KOFF) + ks_ * 32 + kg * 8]; \
      acc[0][nt_] = MFMA16(a0_, b_, acc[0][nt_]);                           \
      acc[1][nt_] = MFMA16(a1_, b_, acc[1][nt_]);                           \
    }                                                                       \
  }

#define RELU_TO_ABUF()                                                      \
  _Pragma("unroll")                                                         \
  for (int mt_ = 0; mt_ < 2; ++mt_) {                                       \
    _Pragma("unroll")                                                       \
    for (int nt_ = 0; nt_ < 8; ++nt_) {                                     \
      _Pragma("unroll")                                                     \
      for (int i_ = 0; i_ < 4; ++i_) {                                      \
        int row_ = rw + 16 * mt_ + kg * 4 + i_;                             \
        Abuf[row_ * PADB + nt_ * 16 + lr] = f2bf(fmaxf(acc[mt_][nt_][i_], 0.f)); \
      }                                                                     \
    }                                                                       \
  }

#define LN_STATS2(MARR, RARR)                                               \
  float MARR[2][4], RARR[2][4];                                             \
  _Pragma("unroll")                                                         \
  for (int mt_ = 0; mt_ < 2; ++mt_) {                                       \
    _Pragma("unroll")                                                       \
    for (int i_ = 0; i_ < 4; ++i_) {                                        \
      float s_ = 0.f;                                                       \
      _Pragma("unroll")                                                     \
      for (int nt_ = 0; nt_ < 8; ++nt_) s_ += acc[mt_][nt_][i_];            \
      s_ += __shfl_xor(s_, 1); s_ += __shfl_xor(s_, 2);                     \
      s_ += __shfl_xor(s_, 4); s_ += __shfl_xor(s_, 8);                     \
      float m_ = s_ * (1.f / 128.f);                                        \
      float v_ = 0.f;                                                       \
      _Pragma("unroll")                                                     \
      for (int nt_ = 0; nt_ < 8; ++nt_) {                                   \
        float d_ = acc[mt_][nt_][i_] - m_; v_ = fmaf(d_, d_, v_);           \
      }                                                                     \
      v_ += __shfl_xor(v_, 1); v_ += __shfl_xor(v_, 2);                     \
      v_ += __shfl_xor(v_, 4); v_ += __shfl_xor(v_, 8);                     \
      MARR[mt_][i_] = m_;                                                   \
      RARR[mt_][i_] = rsqrtf(v_ * (1.f / 128.f) + LN_EPS);                  \
    }                                                                       \
  }

// ---- weight prep: fp32 [steps][Ksrc][N] -> bf16 [steps][N][Kdst] ----
__global__ void k_prep_w(const float* __restrict__ src, ushort_t* __restrict__ dst,
                         int Ksrc, int Kdst, int N, int steps) {
  const size_t total = (size_t)steps * N * Kdst;
  for (size_t idx = (size_t)blockIdx.x * blockDim.x + threadIdx.x; idx < total;
       idx += (size_t)gridDim.x * blockDim.x) {
    int k = (int)(idx % Kdst);
    size_t tmp = idx / Kdst;
    int n = (int)(tmp % N);
    int s = (int)(tmp / N);
    float v = (k < Ksrc) ? src[((size_t)s * Ksrc + k) * N + n] : 0.f;
    dst[idx] = f2bf(v);
  }
}

// ---- counting sort of edges by receiver ----
__global__ void k_hist(const int* __restrict__ recv, int* __restrict__ cnt) {
  int e = blockIdx.x * 256 + threadIdx.x;
  if (e < NE) atomicAdd(&cnt[recv[e]], 1);
}

__global__ __launch_bounds__(256)
void k_scan(const int* __restrict__ cnt, int* __restrict__ row_start) {
  __shared__ int part[256];
  const int t = threadIdx.x;
  const int base = t * 40;                 // 256*40 = 10240 >= NN
  int sum = 0;
  for (int i = 0; i < 40; ++i) {
    int b = base + i;
    if (b < NN) sum += cnt[b];
  }
  part[t] = sum;
  __syncthreads();
  for (int off = 1; off < 256; off <<= 1) {
    int v = part[t];
    int u = (t >= off) ? part[t - off] : 0;
    __syncthreads();
    part[t] = v + u;
    __syncthreads();
  }
  int run = (t == 0) ? 0 : part[t - 1];
  for (int i = 0; i < 40; ++i) {
    int b = base + i;
    if (b < NN) { row_start[b] = run; run += cnt[b]; }
  }
  if (t == 255) row_start[NN] = run;       // == NE
}

__global__ void k_scatter(const int* __restrict__ send, const int* __restrict__ recv,
                          const int* __restrict__ row_start, int* __restrict__ cursor,
                          int* __restrict__ esrc, int* __restrict__ sSend,
                          int* __restrict__ sRecv) {
  int e = blockIdx.x * 256 + threadIdx.x;
  if (e >= NE) return;
  int r = recv[e];
  int pos = row_start[r] + atomicAdd(&cursor[r], 1);
  esrc[pos] = e;
  sSend[pos] = send[e];
  sRecv[pos] = r;
}

// ---- node encoder: concat(29)->128->128->128, LN ----
__global__ __launch_bounds__(256, 2)
void k_enc_node_m(const float* __restrict__ vh, const float* __restrict__ vm,
                  const float* __restrict__ bd, const float* __restrict__ fc,
                  const ushort_t* __restrict__ Wt0, const float* __restrict__ b0,
                  const ushort_t* __restrict__ Wt1, const float* __restrict__ b1,
                  const ushort_t* __restrict__ Wt2, const float* __restrict__ b2,
                  const float* __restrict__ lns, const float* __restrict__ lno,
                  float* __restrict__ nodes_f, ushort_t* __restrict__ nodes_bf) {
  __shared__ ushort_t Abuf[128 * PADB];
  __shared__ ushort_t Wbuf[128 * PADB];
  const int t = threadIdx.x;
  const int lane = t & 63, wid = t >> 6;
  const int lr = lane & 15, kg = lane >> 4;
  const int rw = wid * 32;
  const int n0 = blockIdx.x * 128;

  for (int idx = t; idx < 128 * 32; idx += 256) {
    int r = idx >> 5, k = idx & 31;
    int ng = n0 + r;
    float v = 0.f;
    if (ng < NN) {
      if (k < 15)      v = vh[(size_t)ng * 15 + k];
      else if (k < 20) v = vm[(size_t)ng * 5 + (k - 15)];
      else if (k < 26) v = bd[(size_t)ng * 6 + (k - 20)];
      else if (k < 29) v = fc[(size_t)ng * 3 + (k - 26)];
    }
    Abuf[r * PADB + k] = f2bf(v);
  }
  {
    const ushort_t* src = Wt0 + (t >> 1) * 32 + (t & 1) * 16;
    ushort_t* dst = &Wbuf[(t >> 1) * PADB + (t & 1) * 16];
    *(uint4*)dst = *(const uint4*)src;
    *(uint4*)(dst + 8) = *(const uint4*)(src + 8);
  }
  f32x4 acc[2][8];
  INIT_ACC(b0)
  __syncthreads();
  {
    short8 a0_ = *(const short8*)&Abuf[(rw + lr) * PADB + kg * 8];
    short8 a1_ = *(const short8*)&Abuf[(rw + 16 + lr) * PADB + kg * 8];
#pragma unroll
    for (int nt_ = 0; nt_ < 8; ++nt_) {
      short8 b_ = *(const short8*)&Wbuf[(nt_ * 16 + lr) * PADB + kg * 8];
      acc[0][nt_] = MFMA16(a0_, b_, acc[0][nt_]);
      acc[1][nt_] = MFMA16(a1_, b_, acc[1][nt_]);
    }
  }
  __syncthreads();
  RELU_TO_ABUF()
  INIT_ACC(b1)
  STAGE_WT(Wt1, 128, 0)
  __syncthreads();
  MFMA_K128()
  __syncthreads();
  RELU_TO_ABUF()
  INIT_ACC(b2)
  STAGE_WT(Wt2, 128, 0)
  __syncthreads();
  MFMA_K128()

  LN_STATS2(lmean, lrstd)
  float sv[8], ov[8];
#pragma unroll
  for (int nt = 0; nt < 8; ++nt) { sv[nt] = lns[nt * 16 + lr]; ov[nt] = lno[nt * 16 + lr]; }
#pragma unroll
  for (int mt = 0; mt < 2; ++mt)
#pragma unroll
    for (int i = 0; i < 4; ++i) {
      int row = rw + 16 * mt + kg * 4 + i;
      int ng = n0 + row;
      if (ng < NN) {
#pragma unroll
        for (int nt = 0; nt < 8; ++nt) {
          float o = (acc[mt][nt][i] - lmean[mt][i]) * lrstd[mt][i] * sv[nt] + ov[nt];
          size_t idx = (size_t)ng * LDIM + nt * 16 + lr;
          nodes_f[idx] = o;
          nodes_bf[idx] = f2bf(o);
        }
      }
    }
}

// ---- edge encoder (sorted order, gathers via esrc); flat contiguous store ----
__global__ __launch_bounds__(256, 2)
void k_enc_edge_m(const float* __restrict__ rel_disp, const float* __restrict__ rel_dist,
                  const int* __restrict__ esrc,
                  const ushort_t* __restrict__ Wt0, const float* __restrict__ b0,
                  const ushort_t* __restrict__ Wt1, const float* __restrict__ b1,
                  const ushort_t* __restrict__ Wt2, const float* __restrict__ b2,
                  const float* __restrict__ lns, const float* __restrict__ lno,
                  float* __restrict__ edges_f) {
  __shared__ ushort_t smem[2 * 128 * PADB];
  __shared__ int eidx[128];
  ushort_t* Abuf = smem;
  ushort_t* Wbuf = smem + 128 * PADB;
  const int t = threadIdx.x;
  const int lane = t & 63, wid = t >> 6;
  const int lr = lane & 15, kg = lane >> 4;
  const int rw = wid * 32;
  const int e0 = blockIdx.x * 128;

  if (t < 128) eidx[t] = (e0 + t < NE) ? esrc[e0 + t] : 0;
  __syncthreads();

  for (int idx = t; idx < 128 * 32; idx += 256) {
    int r = idx >> 5, k = idx & 31;
    float v = 0.f;
    if (e0 + r < NE) {
      int eo = eidx[r];
      if (k < 3)       v = rel_disp[(size_t)eo * 3 + k];
      else if (k == 3) v = rel_dist[eo];
    }
    Abuf[r * PADB + k] = f2bf(v);
  }
  {
    const ushort_t* src = Wt0 + (t >> 1) * 32 + (t & 1) * 16;
    ushort_t* dst = &Wbuf[(t >> 1) * PADB + (t & 1) * 16];
    *(uint4*)dst = *(const uint4*)src;
    *(uint4*)(dst + 8) = *(const uint4*)(src + 8);
  }
  f32x4 acc[2][8];
  INIT_ACC(b0)
  __syncthreads();
  {
    short8 a0_ = *(const short8*)&Abuf[(rw + lr) * PADB + kg * 8];
    short8 a1_ = *(const short8*)&Abuf[(rw + 16 + lr) * PADB + kg * 8];
#pragma unroll
    for (int nt_ = 0; nt_ < 8; ++nt_) {
      short8 b_ = *(const short8*)&Wbuf[(nt_ * 16 + lr) * PADB + kg * 8];
      acc[0][nt_] = MFMA16(a0_, b_, acc[0][nt_]);
      acc[1][nt_] = MFMA16(a1_, b_, acc[1][nt_]);
    }
  }
  __syncthreads();
  RELU_TO_ABUF()
  INIT_ACC(b1)
  STAGE_WT(Wt1, 128, 0)
  __syncthreads();
  MFMA_K128()
  __syncthreads();
  RELU_TO_ABUF()
  INIT_ACC(b2)
  STAGE_WT(Wt2, 128, 0)
  __syncthreads();
  MFMA_K128()

  LN_STATS2(lmean, lrstd)
  float sv[8], ov[8];
#pragma unroll
  for (int nt = 0; nt < 8; ++nt) { sv[nt] = lns[nt * 16 + lr]; ov[nt] = lno[nt * 16 + lr]; }

  float* fbuf = (float*)smem;
  __syncthreads();                 // all MFMA LDS reads done
#pragma unroll
  for (int mt_ = 0; mt_ < 2; ++mt_)
#pragma unroll
    for (int i_ = 0; i_ < 4; ++i_) {
      int row_ = rw + 16 * mt_ + kg * 4 + i_;
#pragma unroll
      for (int nt_ = 0; nt_ < 8; ++nt_)
        fbuf[row_ * 132 + nt_ * 16 + lr] =
            (acc[mt_][nt_][i_] - lmean[mt_][i_]) * lrstd[mt_][i_] * sv[nt_] + ov[nt_];
    }
  __syncthreads();
  // flat contiguous store: each instruction = 64 lanes x 16B = 1KB contiguous
#pragma unroll
  for (int q = 0; q < 16; ++q) {
    int F = wid * 4096 + q * 256 + lane * 4;   // float index within block tile
    int row = F >> 7, col = F & 127;
    if (e0 + row < NE) {
      float4 v = *(const float4*)&fbuf[row * 132 + col];
      *(float4*)&edges_f[(size_t)e0 * LDIM + F] = v;
    }
  }
}

// ---- processor edge block: barrier-minimal, W from L2, wave-private Abuf ----
__global__ __launch_bounds__(256, 2)
void k_proc_edge_m(const ushort_t* __restrict__ nodes_bf, float* __restrict__ edges_f,
                   float* __restrict__ aggr,
                   const int* __restrict__ sSend, const int* __restrict__ sRecv,
                   const ushort_t* __restrict__ Wt0, const float* __restrict__ b0,
                   const ushort_t* __restrict__ Wt1, const float* __restrict__ b1,
                   const ushort_t* __restrict__ Wt2, const float* __restrict__ b2,
                   const float* __restrict__ lns, const float* __restrict__ lno) {
  // Abuf (bf16, 34816B) aliased with fbuf (fp32 64x132 = 33792B, epilogue only)
  __shared__ __align__(16) unsigned char smem[128 * PADB * 2];
  __shared__ int ridxs[128];
  ushort_t* Abuf = (ushort_t*)smem;
  float* fbuf = (float*)smem;
  const int t = threadIdx.x;
  const int lane = t & 63, wid = t >> 6;
  const int lr = lane & 15, kg = lane >> 4;
  const int rw = wid * 32;
  const int e0 = blockIdx.x * 128;

  if (t < 128) ridxs[t] = (e0 + t < NE) ? sRecv[e0 + t] : -1;
  // (ridxs first read only after later barriers - no sync needed here)

  // per-lane gather indices for this wave's A rows (rw+lr, rw+16+lr)
  const int er0 = e0 + rw + lr, er1 = e0 + rw + 16 + lr;
  const int s0r = (er0 < NE) ? sSend[er0] : 0;
  const int s1r = (er1 < NE) ? sSend[er1] : 0;
  const int r0r = (er0 < NE) ? sRecv[er0] : 0;
  const int r1r = (er1 < NE) ? sRecv[er1] : 0;

  // issue edge-tile flat loads early: HBM latency hides under seg0/seg1 MFMA
  float4 eold[16];
#pragma unroll
  for (int q = 0; q < 16; ++q) {
    int F = wid * 4096 + q * 256 + lane * 4;
    int row = F >> 7;
    if (e0 + row < NE) eold[q] = *(const float4*)&edges_f[(size_t)e0 * LDIM + F];
    else { eold[q].x = eold[q].y = eold[q].z = eold[q].w = 0.f; }
  }

  f32x4 acc[2][8];
  INIT_ACC(b0)

  // seg0: A = nodes[senders] gathered per-lane (L2), B from global (L2)
  {
    const ushort_t* a0p = nodes_bf + (size_t)s0r * LDIM;
    const ushort_t* a1p = nodes_bf + (size_t)s1r * LDIM;
    MFMA_K128_GAW(a0p, a1p, Wt0, 384, 0)
  }
  // seg1: A = nodes[receivers]
  {
    const ushort_t* a0p = nodes_bf + (size_t)r0r * LDIM;
    const ushort_t* a1p = nodes_bf + (size_t)r1r * LDIM;
    MFMA_K128_GAW(a0p, a1p, Wt0, 384, 128)
  }
  // seg2: edge features -> wave-private Abuf rows (no barrier), then MFMA
#pragma unroll
  for (int q = 0; q < 16; ++q) {
    int F = wid * 4096 + q * 256 + lane * 4;
    int row = F >> 7, col = F & 127;
    ushort4 hv;
    hv.x = f2bf(eold[q].x); hv.y = f2bf(eold[q].y);
    hv.z = f2bf(eold[q].z); hv.w = f2bf(eold[q].w);
    *(ushort4*)&Abuf[row * PADB + col] = hv;
  }
  MFMA_K128_GW(Wt0, 384, 256)

  // layers 1,2: RELU transpose through wave-private Abuf rows - no barriers
  RELU_TO_ABUF()
  INIT_ACC(b1)
  MFMA_K128_GW(Wt1, 128, 0)
  RELU_TO_ABUF()
  INIT_ACC(b2)
  MFMA_K128_GW(Wt2, 128, 0)

  LN_STATS2(lmean, lrstd)
  float sv[8], ov[8];
#pragma unroll
  for (int nt = 0; nt < 8; ++nt) { sv[nt] = lns[nt * 16 + lr]; ov[nt] = lno[nt * 16 + lr]; }

  __syncthreads();   // all Abuf reads done; fbuf (aliased) epilogue begins

  // two-pass epilogue over 64-row windows: LN->fbuf, residual store, fused aggr
#pragma unroll
  for (int p = 0; p < 2; ++p) {
    if (p) __syncthreads();          // pass-0 readers done before overwrite
    if ((wid >> 1) == p) {
#pragma unroll
      for (int mt = 0; mt < 2; ++mt)
#pragma unroll
        for (int i = 0; i < 4; ++i) {
          int lrow = (rw - p * 64) + 16 * mt + kg * 4 + i;
#pragma unroll
          for (int nt = 0; nt < 8; ++nt)
            fbuf[lrow * 132 + nt * 16 + lr] =
                (acc[mt][nt][i] - lmean[mt][i]) * lrstd[mt][i] * sv[nt] + ov[nt];
        }
    }
    __syncthreads();
    if ((wid >> 1) == p) {
      // residual update, flat contiguous, eold from registers
#pragma unroll
      for (int q = 0; q < 16; ++q) {
        int F = wid * 4096 + q * 256 + lane * 4;
        int row = F >> 7, col = F & 127;
        if (e0 + row < NE) {
          int lrow = row - p * 64;
          float4 nv = *(const float4*)&fbuf[lrow * 132 + col];
          nv.x += eold[q].x; nv.y += eold[q].y;
          nv.z += eold[q].z; nv.w += eold[q].w;
          *(float4*)&edges_f[(size_t)e0 * LDIM + F] = nv;
        }
      }
    }
    // fused segment-sum: thread owns column c over a 32-row strip
    {
      const int c = t & 127, sub = t >> 7;
      const int rA = p * 64 + sub * 32, rB = rA + 32;
      float run = 0.f;
      int cur = ridxs[rA];
      for (int r = rA; r < rB; ++r) {
        int rid = ridxs[r];
        if (rid != cur) {
          if (cur >= 0) atomicAdd(&aggr[(size_t)cur * LDIM + c], run);
          run = 0.f;
          cur = rid;
        }
        run += fbuf[(r - p * 64) * 132 + c];
      }
      if (cur >= 0) atomicAdd(&aggr[(size_t)cur * LDIM + c], run);
    }
  }
}

// ---- processor node block: [nd, aggr_f32](256)->MLP->LN; nd += n_new ----
__global__ __launch_bounds__(256, 2)
void k_proc_node_m(float* __restrict__ nodes_f, ushort_t* __restrict__ nodes_bf,
                   const float* __restrict__ aggr,
                   const ushort_t* __restrict__ Wt0, const float* __restrict__ b0,
                   const ushort_t* __restrict__ Wt1, const float* __restrict__ b1,
                   const ushort_t* __restrict__ Wt2, const float* __restrict__ b2,
                   const float* __restrict__ lns, const float* __restrict__ lno) {
  __shared__ ushort_t Abuf[128 * PADB];
  __shared__ ushort_t Wbuf[128 * PADB];
  const int t = threadIdx.x;
  const int lane = t & 63, wid = t >> 6;
  const int lr = lane & 15, kg = lane >> 4;
  const int rw = wid * 32;
  const int n0 = blockIdx.x * 128;

  f32x4 acc[2][8];
  INIT_ACC(b0)

#pragma unroll
  for (int seg = 0; seg < 2; ++seg) {
    if (seg) __syncthreads();
    {
      const int r = t >> 1, h = t & 1;
      const int ng = n0 + r;
      ushort_t* dst = &Abuf[r * PADB + h * 64];
      if (ng < NN) {
        if (seg == 0) {
          const ushort_t* src = nodes_bf + (size_t)ng * LDIM + h * 64;
#pragma unroll
          for (int q = 0; q < 8; ++q)
            *(uint4*)(dst + q * 8) = *(const uint4*)(src + q * 8);
        } else {
          const float* src = aggr + (size_t)ng * LDIM + h * 64;
#pragma unroll
          for (int q = 0; q < 16; ++q) {
            float4 fv = *(const float4*)(src + q * 4);
            ushort4 hv;
            hv.x = f2bf(fv.x); hv.y = f2bf(fv.y); hv.z = f2bf(fv.z); hv.w = f2bf(fv.w);
            *(ushort4*)(dst + q * 4) = hv;
          }
        }
      } else {
        uint4 z; z.x = z.y = z.z = z.w = 0u;
#pragma unroll
        for (int q = 0; q < 8; ++q) *(uint4*)(dst + q * 8) = z;
      }
    }
    STAGE_WT(Wt0, 256, seg * 128)
    __syncthreads();
    MFMA_K128()
  }
  __syncthreads();
  RELU_TO_ABUF()
  INIT_ACC(b1)
  STAGE_WT(Wt1, 128, 0)
  __syncthreads();
  MFMA_K128()
  __syncthreads();
  RELU_TO_ABUF()
  INIT_ACC(b2)
  STAGE_WT(Wt2, 128, 0)
  __syncthreads();
  MFMA_K128()

  LN_STATS2(lmean, lrstd)
  float sv[8], ov[8];
#pragma unroll
  for (int nt = 0; nt < 8; ++nt) { sv[nt] = lns[nt * 16 + lr]; ov[nt] = lno[nt * 16 + lr]; }
#pragma unroll
  for (int mt = 0; mt < 2; ++mt)
#pragma unroll
    for (int i = 0; i < 4; ++i) {
      int row = rw + 16 * mt + kg * 4 + i;
      int ng = n0 + row;
      if (ng < NN) {
#pragma unroll
        for (int nt = 0; nt < 8; ++nt) {
          float o = (acc[mt][nt][i] - lmean[mt][i]) * lrstd[mt][i] * sv[nt] + ov[nt];
          size_t idx = (size_t)ng * LDIM + nt * 16 + lr;
          float nv = nodes_f[idx] + o;
          nodes_f[idx] = nv;
          nodes_bf[idx] = f2bf(nv);
        }
      }
    }
}

// ---- decoder: 128->128->128->3 (no LN) ----
__global__ __launch_bounds__(256, 2)
void k_dec_m(const ushort_t* __restrict__ nodes_bf,
             const ushort_t* __restrict__ Wt0, const float* __restrict__ b0,
             const ushort_t* __restrict__ Wt1, const float* __restrict__ b1,
             const float* __restrict__ W2f, const float* __restrict__ b2,
             float* __restrict__ out) {
  __shared__ ushort_t Abuf[128 * PADB];
  __shared__ ushort_t Wbuf[128 * PADB];
  const int t = threadIdx.x;
  const int lane = t & 63, wid = t >> 6;
  const int lr = lane & 15, kg = lane >> 4;
  const int rw = wid * 32;
  const int n0 = blockIdx.x * 128;

  {
    const int r = t >> 1, h = t & 1;
    const int ng = n0 + r;
    ushort_t* dst = &Abuf[r * PADB + h * 64];
    if (ng < NN) {
      const ushort_t* src = nodes_bf + (size_t)ng * LDIM + h * 64;
#pragma unroll
      for (int q = 0; q < 8; ++q)
        *(uint4*)(dst + q * 8) = *(const uint4*)(src + q * 8);
    } else {
      uint4 z; z.x = z.y = z.z = z.w = 0u;
#pragma unroll
      for (int q = 0; q < 8; ++q) *(uint4*)(dst + q * 8) = z;
    }
  }
  f32x4 acc[2][8];
  INIT_ACC(b0)
  STAGE_WT(Wt0, 128, 0)
  __syncthreads();
  MFMA_K128()
  __syncthreads();
  RELU_TO_ABUF()
  INIT_ACC(b1)
  STAGE_WT(Wt1, 128, 0)
  __syncthreads();
  MFMA_K128()
  __syncthreads();
  RELU_TO_ABUF()
  __syncthreads();

  if (t < 128) {
    const int ng = n0 + t;
    if (ng < NN) {
      float s0 = b2[0], s1 = b2[1], s2 = b2[2];
      for (int k = 0; k < 128; ++k) {
        float xv = bf2f(Abuf[t * PADB + k]);
        s0 = fmaf(xv, W2f[k * 3 + 0], s0);
        s1 = fmaf(xv, W2f[k * 3 + 1], s1);
        s2 = fmaf(xv, W2f[k * 3 + 2], s2);
      }
      out[(size_t)ng * 3 + 0] = s0;
      out[(size_t)ng * 3 + 1] = s1;
      out[(size_t)ng * 3 + 2] = s2;
    }
  }
}

extern "C" void kernel_launch(void* const* d_in, const int* in_sizes, int n_in,
                              void* d_out, int out_size, void* d_ws, size_t ws_size,
                              hipStream_t stream) {
  const float* vel_hist = (const float*)d_in[0];
  const float* vel_mag  = (const float*)d_in[1];
  const float* bnd      = (const float*)d_in[2];
  const float* force    = (const float*)d_in[3];
  const float* rel_disp = (const float*)d_in[4];
  const float* rel_dist = (const float*)d_in[5];
  const int*   senders   = (const int*)d_in[6];
  const int*   receivers = (const int*)d_in[7];
  const float* en_W0 = (const float*)d_in[8];  const float* en_b0 = (const float*)d_in[9];
  const float* en_W1 = (const float*)d_in[10]; const float* en_b1 = (const float*)d_in[11];
  const float* en_W2 = (const float*)d_in[12]; const float* en_b2 = (const float*)d_in[13];
  const float* ee_W0 = (const float*)d_in[14]; const float* ee_b0 = (const float*)d_in[15];
  const float* ee_W1 = (const float*)d_in[16]; const float* ee_b1 = (const float*)d_in[17];
  const float* ee_W2 = (const float*)d_in[18]; const float* ee_b2 = (const float*)d_in[19];
  const float* pe_W0 = (const float*)d_in[20]; const float* pe_b0 = (const float*)d_in[21];
  const float* pe_W1 = (const float*)d_in[22]; const float* pe_b1 = (const float*)d_in[23];
  const float* pe_W2 = (const float*)d_in[24]; const float* pe_b2 = (const float*)d_in[25];
  const float* pn_W0 = (const float*)d_in[26]; const float* pn_b0 = (const float*)d_in[27];
  const float* pn_W1 = (const float*)d_in[28]; const float* pn_b1 = (const float*)d_in[29];
  const float* pn_W2 = (const float*)d_in[30]; const float* pn_b2 = (const float*)d_in[31];
  const float* de_W0 = (const float*)d_in[32]; const float* de_b0 = (const float*)d_in[33];
  const float* de_W1 = (const float*)d_in[34]; const float* de_b1 = (const float*)d_in[35];
  const float* de_W2 = (const float*)d_in[36]; const float* de_b2 = (const float*)d_in[37];
  const float* en_s = (const float*)d_in[38]; const float* en_o = (const float*)d_in[39];
  const float* ee_s = (const float*)d_in[40]; const float* ee_o = (const float*)d_in[41];
  const float* pe_s = (const float*)d_in[42]; const float* pe_o = (const float*)d_in[43];
  const float* pn_s = (const float*)d_in[44]; const float* pn_o = (const float*)d_in[45];

  // ---- workspace layout ----
  float* nodes_f = (float*)d_ws;                               // NN*128 f32
  float* edges_f = nodes_f + (size_t)NN * LDIM;                // NE*128 f32
  float* aggr    = edges_f + (size_t)NE * LDIM;                // NN*128 f32
  ushort_t* nodes_bf = (ushort_t*)(aggr + (size_t)NN * LDIM);
  ushort_t* w = nodes_bf + (size_t)NN * LDIM;
  ushort_t* wEn0 = w; w += 128 * 32;
  ushort_t* wEn1 = w; w += 128 * 128;
  ushort_t* wEn2 = w; w += 128 * 128;
  ushort_t* wEe0 = w; w += 128 * 32;
  ushort_t* wEe1 = w; w += 128 * 128;
  ushort_t* wEe2 = w; w += 128 * 128;
  ushort_t* wPe0 = w; w += (size_t)NSTEP * 128 * 384;
  ushort_t* wPe1 = w; w += (size_t)NSTEP * 128 * 128;
  ushort_t* wPe2 = w; w += (size_t)NSTEP * 128 * 128;
  ushort_t* wPn0 = w; w += (size_t)NSTEP * 128 * 256;
  ushort_t* wPn1 = w; w += (size_t)NSTEP * 128 * 128;
  ushort_t* wPn2 = w; w += (size_t)NSTEP * 128 * 128;
  ushort_t* wDe0 = w; w += 128 * 128;
  ushort_t* wDe1 = w; w += 128 * 128;
  int* cnt       = (int*)w;
  int* row_start = cnt + NN;          // NN+1
  int* cursor    = row_start + NN + 1;
  int* esrc      = cursor + NN;
  int* sSend     = esrc + NE;
  int* sRecv     = sSend + NE;

  auto prep = [&](const float* src, ushort_t* dst, int Ks, int Kd, int N_, int st) {
    size_t total = (size_t)st * N_ * Kd;
    int blocks = (int)((total + 255) / 256);
    if (blocks > 1024) blocks = 1024;
    k_prep_w<<<blocks, 256, 0, stream>>>(src, dst, Ks, Kd, N_, st);
  };
  prep(en_W0, wEn0, 29, 32, 128, 1);
  prep(en_W1, wEn1, 128, 128, 128, 1);
  prep(en_W2, wEn2, 128, 128, 128, 1);
  prep(ee_W0, wEe0, 4, 32, 128, 1);
  prep(ee_W1, wEe1, 128, 128, 128, 1);
  prep(ee_W2, wEe2, 128, 128, 128, 1);
  prep(pe_W0, wPe0, 384, 384, 128, NSTEP);
  prep(pe_W1, wPe1, 128, 128, 128, NSTEP);
  prep(pe_W2, wPe2, 128, 128, 128, NSTEP);
  prep(pn_W0, wPn0, 256, 256, 128, NSTEP);
  prep(pn_W1, wPn1, 128, 128, 128, NSTEP);
  prep(pn_W2, wPn2, 128, 128, 128, NSTEP);
  prep(de_W0, wDe0, 128, 128, 128, 1);
  prep(de_W1, wDe1, 128, 128, 128, 1);

  // ---- counting sort by receiver ----
  hipMemsetAsync(cnt, 0, NN * sizeof(int), stream);
  hipMemsetAsync(cursor, 0, NN * sizeof(int), stream);
  k_hist<<<(NE + 255) / 256, 256, 0, stream>>>(receivers, cnt);
  k_scan<<<1, 256, 0, stream>>>(cnt, row_start);
  k_scatter<<<(NE + 255) / 256, 256, 0, stream>>>(senders, receivers, row_start,
                                                  cursor, esrc, sSend, sRecv);

  const int NB = (NN + 127) / 128;   // 79
  const int EB = (NE + 127) / 128;   // 1563

  k_enc_node_m<<<NB, 256, 0, stream>>>(vel_hist, vel_mag, bnd, force,
      wEn0, en_b0, wEn1, en_b1, wEn2, en_b2, en_s, en_o, nodes_f, nodes_bf);
  k_enc_edge_m<<<EB, 256, 0, stream>>>(rel_disp, rel_dist, esrc,
      wEe0, ee_b0, wEe1, ee_b1, wEe2, ee_b2, ee_s, ee_o, edges_f);

  for (int s = 0; s < NSTEP; ++s) {
    hipMemsetAsync(aggr, 0, (size_t)NN * LDIM * sizeof(float), stream);
    k_proc_edge_m<<<EB, 256, 0, stream>>>(nodes_bf, edges_f, aggr, sSend, sRecv,
        wPe0 + (size_t)s * 128 * 384, pe_b0 + (size_t)s * LDIM,
        wPe1 + (size_t)s * 128 * 128, pe_b1 + (size_t)s * LDIM,
        wPe2 + (size_t)s * 128 * 128, pe_b2 + (size_t)s * LDIM,
        pe_s + (size_t)s * LDIM, pe_o + (size_t)s * LDIM);
    k_proc_node_m<<<NB, 256, 0, stream>>>(nodes_f, nodes_bf, aggr,
        wPn0 + (size_t)s * 128 * 256, pn_b0 + (size_t)s * LDIM,
        wPn1 + (size_t)s * 128 * 128, pn_b1 + (size_t)s * LDIM,
        wPn2 + (size_t)s * 128 * 128, pn_b2 + (size_t)s * LDIM,
        pn_s + (size_t)s * LDIM, pn_o + (size_t)s * LDIM);
  }

  k_dec_m<<<NB, 256, 0, stream>>>(nodes_bf, wDe0, de_b0, wDe1, de_b1, de_W2, de_b2,
                                  (float*)d_out);
}

// Round 6
// 1462.875 us; speedup vs baseline: 1.7770x; 1.7770x over previous
//
#include <hip/hip_runtime.h>

#define NN 10000
#define NE 200000
#define LDIM 128
#define PADB 136   // bf16 elements per LDS row (128 + 8)
#define NSTEP 10
#define LN_EPS 1e-5f

typedef unsigned short ushort_t;
typedef __attribute__((ext_vector_type(8))) short short8;
typedef __attribute__((ext_vector_type(4))) float f32x4;

#define MFMA16(a, b, c) __builtin_amdgcn_mfma_f32_16x16x32_bf16(a, b, c, 0, 0, 0)

__device__ __forceinline__ ushort_t f2bf(float f) {
  unsigned int u = __float_as_uint(f);
  return (ushort_t)((u + 0x7FFFu + ((u >> 16) & 1u)) >> 16);
}
__device__ __forceinline__ float bf2f(ushort_t h) {
  return __uint_as_float(((unsigned int)h) << 16);
}

// ================= M32 macros (256 thr, 4 waves, 32 rows/wave) — encoders/decoder ====
#define STAGE_WT(WT, KTOT, K0)                                              \
  {                                                                         \
    const ushort_t* src_ = (WT) + (size_t)(t >> 1) * (KTOT) + (K0) + (t & 1) * 64; \
    ushort_t* dst_ = &Wbuf[(t >> 1) * PADB + (t & 1) * 64];                 \
    _Pragma("unroll")                                                       \
    for (int q_ = 0; q_ < 8; ++q_)                                          \
      *(uint4*)(dst_ + q_ * 8) = *(const uint4*)(src_ + q_ * 8);            \
  }

#define INIT_ACC(BG)                                                        \
  _Pragma("unroll")                                                         \
  for (int nt_ = 0; nt_ < 8; ++nt_) {                                       \
    float bv_ = (BG)[nt_ * 16 + lr];                                        \
    acc[0][nt_] = (f32x4){bv_, bv_, bv_, bv_};                              \
    acc[1][nt_] = acc[0][nt_];                                              \
  }

#define MFMA_K128()                                                         \
  _Pragma("unroll")                                                         \
  for (int ks_ = 0; ks_ < 4; ++ks_) {                                       \
    short8 a0_ = *(const short8*)&Abuf[(rw + lr) * PADB + ks_ * 32 + kg * 8];        \
    short8 a1_ = *(const short8*)&Abuf[(rw + 16 + lr) * PADB + ks_ * 32 + kg * 8];   \
    _Pragma("unroll")                                                       \
    for (int nt_ = 0; nt_ < 8; ++nt_) {                                     \
      short8 b_ = *(const short8*)&Wbuf[(nt_ * 16 + lr) * PADB + ks_ * 32 + kg * 8]; \
      acc[0][nt_] = MFMA16(a0_, b_, acc[0][nt_]);                           \
      acc[1][nt_] = MFMA16(a1_, b_, acc[1][nt_]);                           \
    }                                                                       \
  }

#define RELU_TO_ABUF()                                                      \
  _Pragma("unroll")                                                         \
  for (int mt_ = 0; mt_ < 2; ++mt_) {                                       \
    _Pragma("unroll")                                                       \
    for (int nt_ = 0; nt_ < 8; ++nt_) {                                     \
      _Pragma("unroll")                                                     \
      for (int i_ = 0; i_ < 4; ++i_) {                                      \
        int row_ = rw + 16 * mt_ + kg * 4 + i_;                             \
        Abuf[row_ * PADB + nt_ * 16 + lr] = f2bf(fmaxf(acc[mt_][nt_][i_], 0.f)); \
      }                                                                     \
    }                                                                       \
  }

#define LN_STATS2(MARR, RARR)                                               \
  float MARR[2][4], RARR[2][4];                                             \
  _Pragma("unroll")                                                         \
  for (int mt_ = 0; mt_ < 2; ++mt_) {                                       \
    _Pragma("unroll")                                                       \
    for (int i_ = 0; i_ < 4; ++i_) {                                        \
      float s_ = 0.f;                                                       \
      _Pragma("unroll")                                                     \
      for (int nt_ = 0; nt_ < 8; ++nt_) s_ += acc[mt_][nt_][i_];            \
      s_ += __shfl_xor(s_, 1); s_ += __shfl_xor(s_, 2);                     \
      s_ += __shfl_xor(s_, 4); s_ += __shfl_xor(s_, 8);                     \
      float m_ = s_ * (1.f / 128.f);                                        \
      float v_ = 0.f;                                                       \
      _Pragma("unroll")                                                     \
      for (int nt_ = 0; nt_ < 8; ++nt_) {                                   \
        float d_ = acc[mt_][nt_][i_] - m_; v_ = fmaf(d_, d_, v_);           \
      }                                                                     \
      v_ += __shfl_xor(v_, 1); v_ += __shfl_xor(v_, 2);                     \
      v_ += __shfl_xor(v_, 4); v_ += __shfl_xor(v_, 8);                     \
      MARR[mt_][i_] = m_;                                                   \
      RARR[mt_][i_] = rsqrtf(v_ * (1.f / 128.f) + LN_EPS);                  \
    }                                                                       \
  }

// ================= M16 macros (wave owns 16 rows at rw = wid*16) ====================
#define INIT_ACC1(BG)                                                       \
  _Pragma("unroll")                                                         \
  for (int nt_ = 0; nt_ < 8; ++nt_) {                                       \
    float bv_ = (BG)[nt_ * 16 + lr];                                        \
    acc[nt_] = (f32x4){bv_, bv_, bv_, bv_};                                 \
  }

#define MFMA_K128_M16()                                                     \
  _Pragma("unroll")                                                         \
  for (int ks_ = 0; ks_ < 4; ++ks_) {                                       \
    short8 a_ = *(const short8*)&Abuf[(rw + lr) * PADB + ks_ * 32 + kg * 8];         \
    _Pragma("unroll")                                                       \
    for (int nt_ = 0; nt_ < 8; ++nt_) {                                     \
      short8 b_ = *(const short8*)&Wbuf[(nt_ * 16 + lr) * PADB + ks_ * 32 + kg * 8]; \
      acc[nt_] = MFMA16(a_, b_, acc[nt_]);                                  \
    }                                                                       \
  }

#define RELU_TO_ABUF1()                                                     \
  _Pragma("unroll")                                                         \
  for (int nt_ = 0; nt_ < 8; ++nt_) {                                       \
    _Pragma("unroll")                                                       \
    for (int i_ = 0; i_ < 4; ++i_) {                                        \
      int row_ = rw + kg * 4 + i_;                                          \
      Abuf[row_ * PADB + nt_ * 16 + lr] = f2bf(fmaxf(acc[nt_][i_], 0.f));   \
    }                                                                       \
  }

#define LN_STATS1(MARR, RARR)                                               \
  float MARR[4], RARR[4];                                                   \
  _Pragma("unroll")                                                         \
  for (int i_ = 0; i_ < 4; ++i_) {                                          \
    float s_ = 0.f;                                                         \
    _Pragma("unroll")                                                       \
    for (int nt_ = 0; nt_ < 8; ++nt_) s_ += acc[nt_][i_];                   \
    s_ += __shfl_xor(s_, 1); s_ += __shfl_xor(s_, 2);                       \
    s_ += __shfl_xor(s_, 4); s_ += __shfl_xor(s_, 8);                       \
    float m_ = s_ * (1.f / 128.f);                                          \
    float v_ = 0.f;                                                         \
    _Pragma("unroll")                                                       \
    for (int nt_ = 0; nt_ < 8; ++nt_) {                                     \
      float d_ = acc[nt_][i_] - m_; v_ = fmaf(d_, d_, v_);                  \
    }                                                                       \
    v_ += __shfl_xor(v_, 1); v_ += __shfl_xor(v_, 2);                       \
    v_ += __shfl_xor(v_, 4); v_ += __shfl_xor(v_, 8);                       \
    MARR[i_] = m_;                                                          \
    RARR[i_] = rsqrtf(v_ * (1.f / 128.f) + LN_EPS);                         \
  }

// 512-thread W panel stage: thread t copies 64B of row t>>2
#define STAGE_WT512(WT, KTOT, K0)                                           \
  {                                                                         \
    const ushort_t* src_ = (WT) + (size_t)(t >> 2) * (KTOT) + (K0) + (t & 3) * 32; \
    ushort_t* dst_ = &Wbuf[(t >> 2) * PADB + (t & 3) * 32];                 \
    _Pragma("unroll")                                                       \
    for (int q_ = 0; q_ < 4; ++q_)                                          \
      *(uint4*)(dst_ + q_ * 8) = *(const uint4*)(src_ + q_ * 8);            \
  }

// ---- weight prep: fp32 [steps][Ksrc][N] -> bf16 [steps][N][Kdst] ----
__global__ void k_prep_w(const float* __restrict__ src, ushort_t* __restrict__ dst,
                         int Ksrc, int Kdst, int N, int steps) {
  const size_t total = (size_t)steps * N * Kdst;
  for (size_t idx = (size_t)blockIdx.x * blockDim.x + threadIdx.x; idx < total;
       idx += (size_t)gridDim.x * blockDim.x) {
    int k = (int)(idx % Kdst);
    size_t tmp = idx / Kdst;
    int n = (int)(tmp % N);
    int s = (int)(tmp / N);
    float v = (k < Ksrc) ? src[((size_t)s * Ksrc + k) * N + n] : 0.f;
    dst[idx] = f2bf(v);
  }
}

// ---- counting sort of edges by receiver ----
__global__ void k_hist(const int* __restrict__ recv, int* __restrict__ cnt) {
  int e = blockIdx.x * 256 + threadIdx.x;
  if (e < NE) atomicAdd(&cnt[recv[e]], 1);
}

__global__ __launch_bounds__(256)
void k_scan(const int* __restrict__ cnt, int* __restrict__ row_start) {
  __shared__ int part[256];
  const int t = threadIdx.x;
  const int base = t * 40;
  int sum = 0;
  for (int i = 0; i < 40; ++i) {
    int b = base + i;
    if (b < NN) sum += cnt[b];
  }
  part[t] = sum;
  __syncthreads();
  for (int off = 1; off < 256; off <<= 1) {
    int v = part[t];
    int u = (t >= off) ? part[t - off] : 0;
    __syncthreads();
    part[t] = v + u;
    __syncthreads();
  }
  int run = (t == 0) ? 0 : part[t - 1];
  for (int i = 0; i < 40; ++i) {
    int b = base + i;
    if (b < NN) { row_start[b] = run; run += cnt[b]; }
  }
  if (t == 255) row_start[NN] = run;
}

__global__ void k_scatter(const int* __restrict__ send, const int* __restrict__ recv,
                          const int* __restrict__ row_start, int* __restrict__ cursor,
                          int* __restrict__ esrc, int* __restrict__ sSend,
                          int* __restrict__ sRecv) {
  int e = blockIdx.x * 256 + threadIdx.x;
  if (e >= NE) return;
  int r = recv[e];
  int pos = row_start[r] + atomicAdd(&cursor[r], 1);
  esrc[pos] = e;
  sSend[pos] = send[e];
  sRecv[pos] = r;
}

// ---- node encoder: concat(29)->128->128->128, LN ----
__global__ __launch_bounds__(256, 2)
void k_enc_node_m(const float* __restrict__ vh, const float* __restrict__ vm,
                  const float* __restrict__ bd, const float* __restrict__ fc,
                  const ushort_t* __restrict__ Wt0, const float* __restrict__ b0,
                  const ushort_t* __restrict__ Wt1, const float* __restrict__ b1,
                  const ushort_t* __restrict__ Wt2, const float* __restrict__ b2,
                  const float* __restrict__ lns, const float* __restrict__ lno,
                  float* __restrict__ nodes_f, ushort_t* __restrict__ nodes_bf) {
  __shared__ ushort_t Abuf[128 * PADB];
  __shared__ ushort_t Wbuf[128 * PADB];
  const int t = threadIdx.x;
  const int lane = t & 63, wid = t >> 6;
  const int lr = lane & 15, kg = lane >> 4;
  const int rw = wid * 32;
  const int n0 = blockIdx.x * 128;

  for (int idx = t; idx < 128 * 32; idx += 256) {
    int r = idx >> 5, k = idx & 31;
    int ng = n0 + r;
    float v = 0.f;
    if (ng < NN) {
      if (k < 15)      v = vh[(size_t)ng * 15 + k];
      else if (k < 20) v = vm[(size_t)ng * 5 + (k - 15)];
      else if (k < 26) v = bd[(size_t)ng * 6 + (k - 20)];
      else if (k < 29) v = fc[(size_t)ng * 3 + (k - 26)];
    }
    Abuf[r * PADB + k] = f2bf(v);
  }
  {
    const ushort_t* src = Wt0 + (t >> 1) * 32 + (t & 1) * 16;
    ushort_t* dst = &Wbuf[(t >> 1) * PADB + (t & 1) * 16];
    *(uint4*)dst = *(const uint4*)src;
    *(uint4*)(dst + 8) = *(const uint4*)(src + 8);
  }
  f32x4 acc[2][8];
  INIT_ACC(b0)
  __syncthreads();
  {
    short8 a0_ = *(const short8*)&Abuf[(rw + lr) * PADB + kg * 8];
    short8 a1_ = *(const short8*)&Abuf[(rw + 16 + lr) * PADB + kg * 8];
#pragma unroll
    for (int nt_ = 0; nt_ < 8; ++nt_) {
      short8 b_ = *(const short8*)&Wbuf[(nt_ * 16 + lr) * PADB + kg * 8];
      acc[0][nt_] = MFMA16(a0_, b_, acc[0][nt_]);
      acc[1][nt_] = MFMA16(a1_, b_, acc[1][nt_]);
    }
  }
  __syncthreads();
  RELU_TO_ABUF()
  INIT_ACC(b1)
  STAGE_WT(Wt1, 128, 0)
  __syncthreads();
  MFMA_K128()
  __syncthreads();
  RELU_TO_ABUF()
  INIT_ACC(b2)
  STAGE_WT(Wt2, 128, 0)
  __syncthreads();
  MFMA_K128()

  LN_STATS2(lmean, lrstd)
  float sv[8], ov[8];
#pragma unroll
  for (int nt = 0; nt < 8; ++nt) { sv[nt] = lns[nt * 16 + lr]; ov[nt] = lno[nt * 16 + lr]; }
#pragma unroll
  for (int mt = 0; mt < 2; ++mt)
#pragma unroll
    for (int i = 0; i < 4; ++i) {
      int row = rw + 16 * mt + kg * 4 + i;
      int ng = n0 + row;
      if (ng < NN) {
#pragma unroll
        for (int nt = 0; nt < 8; ++nt) {
          float o = (acc[mt][nt][i] - lmean[mt][i]) * lrstd[mt][i] * sv[nt] + ov[nt];
          size_t idx = (size_t)ng * LDIM + nt * 16 + lr;
          nodes_f[idx] = o;
          nodes_bf[idx] = f2bf(o);
        }
      }
    }
}

// ---- edge encoder (sorted order); flat contiguous store ----
__global__ __launch_bounds__(256, 2)
void k_enc_edge_m(const float* __restrict__ rel_disp, const float* __restrict__ rel_dist,
                  const int* __restrict__ esrc,
                  const ushort_t* __restrict__ Wt0, const float* __restrict__ b0,
                  const ushort_t* __restrict__ Wt1, const float* __restrict__ b1,
                  const ushort_t* __restrict__ Wt2, const float* __restrict__ b2,
                  const float* __restrict__ lns, const float* __restrict__ lno,
                  float* __restrict__ edges_f) {
  __shared__ ushort_t smem[2 * 128 * PADB];
  __shared__ int eidx[128];
  ushort_t* Abuf = smem;
  ushort_t* Wbuf = smem + 128 * PADB;
  const int t = threadIdx.x;
  const int lane = t & 63, wid = t >> 6;
  const int lr = lane & 15, kg = lane >> 4;
  const int rw = wid * 32;
  const int e0 = blockIdx.x * 128;

  if (t < 128) eidx[t] = (e0 + t < NE) ? esrc[e0 + t] : 0;
  __syncthreads();

  for (int idx = t; idx < 128 * 32; idx += 256) {
    int r = idx >> 5, k = idx & 31;
    float v = 0.f;
    if (e0 + r < NE) {
      int eo = eidx[r];
      if (k < 3)       v = rel_disp[(size_t)eo * 3 + k];
      else if (k == 3) v = rel_dist[eo];
    }
    Abuf[r * PADB + k] = f2bf(v);
  }
  {
    const ushort_t* src = Wt0 + (t >> 1) * 32 + (t & 1) * 16;
    ushort_t* dst = &Wbuf[(t >> 1) * PADB + (t & 1) * 16];
    *(uint4*)dst = *(const uint4*)src;
    *(uint4*)(dst + 8) = *(const uint4*)(src + 8);
  }
  f32x4 acc[2][8];
  INIT_ACC(b0)
  __syncthreads();
  {
    short8 a0_ = *(const short8*)&Abuf[(rw + lr) * PADB + kg * 8];
    short8 a1_ = *(const short8*)&Abuf[(rw + 16 + lr) * PADB + kg * 8];
#pragma unroll
    for (int nt_ = 0; nt_ < 8; ++nt_) {
      short8 b_ = *(const short8*)&Wbuf[(nt_ * 16 + lr) * PADB + kg * 8];
      acc[0][nt_] = MFMA16(a0_, b_, acc[0][nt_]);
      acc[1][nt_] = MFMA16(a1_, b_, acc[1][nt_]);
    }
  }
  __syncthreads();
  RELU_TO_ABUF()
  INIT_ACC(b1)
  STAGE_WT(Wt1, 128, 0)
  __syncthreads();
  MFMA_K128()
  __syncthreads();
  RELU_TO_ABUF()
  INIT_ACC(b2)
  STAGE_WT(Wt2, 128, 0)
  __syncthreads();
  MFMA_K128()

  LN_STATS2(lmean, lrstd)
  float sv[8], ov[8];
#pragma unroll
  for (int nt = 0; nt < 8; ++nt) { sv[nt] = lns[nt * 16 + lr]; ov[nt] = lno[nt * 16 + lr]; }

  float* fbuf = (float*)smem;
  __syncthreads();
#pragma unroll
  for (int mt_ = 0; mt_ < 2; ++mt_)
#pragma unroll
    for (int i_ = 0; i_ < 4; ++i_) {
      int row_ = rw + 16 * mt_ + kg * 4 + i_;
#pragma unroll
      for (int nt_ = 0; nt_ < 8; ++nt_)
        fbuf[row_ * 132 + nt_ * 16 + lr] =
            (acc[mt_][nt_][i_] - lmean[mt_][i_]) * lrstd[mt_][i_] * sv[nt_] + ov[nt_];
    }
  __syncthreads();
#pragma unroll
  for (int q = 0; q < 16; ++q) {
    int F = wid * 4096 + q * 256 + lane * 4;
    int row = F >> 7, col = F & 127;
    if (e0 + row < NE) {
      float4 v = *(const float4*)&fbuf[row * 132 + col];
      *(float4*)&edges_f[(size_t)e0 * LDIM + F] = v;
    }
  }
}

// ---- processor edge block: 512 thr, 8 waves, M16/wave, LDS A+W, fused aggr ----
__global__ __launch_bounds__(512, 4)
void k_proc_edge_m(const ushort_t* __restrict__ nodes_bf, float* __restrict__ edges_f,
                   float* __restrict__ aggr,
                   const int* __restrict__ sSend, const int* __restrict__ sRecv,
                   const ushort_t* __restrict__ Wt0, const float* __restrict__ b0,
                   const ushort_t* __restrict__ Wt1, const float* __restrict__ b1,
                   const ushort_t* __restrict__ Wt2, const float* __restrict__ b2,
                   const float* __restrict__ lns, const float* __restrict__ lno) {
  __shared__ ushort_t smem[2 * 128 * PADB];   // Abuf + Wbuf; fbuf aliased in epilogue
  __shared__ int sidx[128], ridxs[128];
  ushort_t* Abuf = smem;
  ushort_t* Wbuf = smem + 128 * PADB;
  const int t = threadIdx.x;
  const int lane = t & 63, wid = t >> 6;          // wid 0..7
  const int lr = lane & 15, kg = lane >> 4;
  const int rw = wid * 16;                        // wave owns rows [rw, rw+16)
  const int e0 = blockIdx.x * 128;

  if (t < 128)       sidx[t] = (e0 + t < NE) ? sSend[e0 + t] : 0;
  else if (t < 256)  ridxs[t - 128] = (e0 + t - 128 < NE) ? sRecv[e0 + t - 128] : -1;

  // early flat loads of old edge tile (32 floats/thread)
  float4 eold[8];
#pragma unroll
  for (int q = 0; q < 8; ++q) {
    int F = q * 2048 + t * 4;
    int row = F >> 7;
    if (e0 + row < NE) eold[q] = *(const float4*)&edges_f[(size_t)e0 * LDIM + F];
    else { eold[q].x = eold[q].y = eold[q].z = eold[q].w = 0.f; }
  }

  f32x4 acc[8];
  INIT_ACC1(b0)

#pragma unroll
  for (int seg = 0; seg < 3; ++seg) {
    __syncthreads();                       // seg0: sidx/ridxs ready; else prev Abuf reads done
    if (seg < 2) {
      const int r = t >> 2, h = t & 3;     // 128 rows, 64B quarter each
      const int srow = (seg == 0) ? sidx[r] : ((ridxs[r] < 0) ? 0 : ridxs[r]);
      const ushort_t* src = nodes_bf + (size_t)srow * LDIM + h * 32;
      ushort_t* dst = &Abuf[r * PADB + h * 32];
#pragma unroll
      for (int q = 0; q < 4; ++q)
        *(uint4*)(dst + q * 8) = *(const uint4*)(src + q * 8);
    } else {
#pragma unroll
      for (int q = 0; q < 8; ++q) {
        int F = q * 2048 + t * 4;
        int row = F >> 7, col = F & 127;
        ushort4 hv;
        hv.x = f2bf(eold[q].x); hv.y = f2bf(eold[q].y);
        hv.z = f2bf(eold[q].z); hv.w = f2bf(eold[q].w);
        *(ushort4*)&Abuf[row * PADB + col] = hv;
      }
    }
    STAGE_WT512(Wt0, 384, seg * 128)
    __syncthreads();
    MFMA_K128_M16()
  }

  // layers 1,2: RELU writes are wave-private rows (no barrier); Wbuf swap needs barriers
  RELU_TO_ABUF1()
  INIT_ACC1(b1)
  __syncthreads();
  STAGE_WT512(Wt1, 128, 0)
  __syncthreads();
  MFMA_K128_M16()
  RELU_TO_ABUF1()
  INIT_ACC1(b2)
  __syncthreads();
  STAGE_WT512(Wt2, 128, 0)
  __syncthreads();
  MFMA_K128_M16()

  LN_STATS1(lmean, lrstd)
  float sv[8], ov[8];
#pragma unroll
  for (int nt = 0; nt < 8; ++nt) { sv[nt] = lns[nt * 16 + lr]; ov[nt] = lno[nt * 16 + lr]; }

  float* fbuf = (float*)smem;              // 128 x 132 fp32 = 67584B over Abuf+Wbuf
  __syncthreads();                         // all smem reads done
#pragma unroll
  for (int i = 0; i < 4; ++i) {
    int row = rw + kg * 4 + i;
#pragma unroll
    for (int nt = 0; nt < 8; ++nt)
      fbuf[row * 132 + nt * 16 + lr] =
          (acc[nt][i] - lmean[i]) * lrstd[i] * sv[nt] + ov[nt];
  }
  __syncthreads();

  // residual update, flat contiguous, eold from registers
#pragma unroll
  for (int q = 0; q < 8; ++q) {
    int F = q * 2048 + t * 4;
    int row = F >> 7, col = F & 127;
    if (e0 + row < NE) {
      float4 nv = *(const float4*)&fbuf[row * 132 + col];
      nv.x += eold[q].x; nv.y += eold[q].y;
      nv.z += eold[q].z; nv.w += eold[q].w;
      *(float4*)&edges_f[(size_t)e0 * LDIM + F] = nv;
    }
  }

  // fused segment-sum: thread owns column c over a 32-row strip
  {
    const int c = t & 127, sub = t >> 7;   // 4 strips of 32 rows
    const int rA = sub * 32, rB = rA + 32;
    float run = 0.f;
    int cur = ridxs[rA];
    for (int r = rA; r < rB; ++r) {
      int rid = ridxs[r];
      if (rid != cur) {
        if (cur >= 0) atomicAdd(&aggr[(size_t)cur * LDIM + c], run);
        run = 0.f;
        cur = rid;
      }
      run += fbuf[r * 132 + c];
    }
    if (cur >= 0) atomicAdd(&aggr[(size_t)cur * LDIM + c], run);
  }
}

// ---- processor node block: 64-row tile, 256 thr, M16/wave; zeroes aggr after read ----
__global__ __launch_bounds__(256, 3)
void k_proc_node_m(float* __restrict__ nodes_f, ushort_t* __restrict__ nodes_bf,
                   float* __restrict__ aggr,
                   const ushort_t* __restrict__ Wt0, const float* __restrict__ b0,
                   const ushort_t* __restrict__ Wt1, const float* __restrict__ b1,
                   const ushort_t* __restrict__ Wt2, const float* __restrict__ b2,
                   const float* __restrict__ lns, const float* __restrict__ lno) {
  __shared__ ushort_t Abuf[64 * PADB];     // 17408B
  __shared__ ushort_t Wbuf[128 * PADB];    // 34816B
  const int t = threadIdx.x;
  const int lane = t & 63, wid = t >> 6;   // wid 0..3
  const int lr = lane & 15, kg = lane >> 4;
  const int rw = wid * 16;                 // rows [rw, rw+16) of 64
  const int n0 = blockIdx.x * 64;

  f32x4 acc[8];
  INIT_ACC1(b0)

#pragma unroll
  for (int seg = 0; seg < 2; ++seg) {
    if (seg) __syncthreads();
    {
      const int r = t >> 2, h = t & 3;     // 64 rows, 64B quarter
      const int ng = n0 + r;
      ushort_t* dst = &Abuf[r * PADB + h * 32];
      if (ng < NN) {
        if (seg == 0) {
          const ushort_t* src = nodes_bf + (size_t)ng * LDIM + h * 32;
#pragma unroll
          for (int q = 0; q < 4; ++q)
            *(uint4*)(dst + q * 8) = *(const uint4*)(src + q * 8);
        } else {
          float* srcf = aggr + (size_t)ng * LDIM + h * 32;
          float4 z4; z4.x = z4.y = z4.z = z4.w = 0.f;
#pragma unroll
          for (int q = 0; q < 8; ++q) {
            float4 fv = *(const float4*)(srcf + q * 4);
            ushort4 hv;
            hv.x = f2bf(fv.x); hv.y = f2bf(fv.y); hv.z = f2bf(fv.z); hv.w = f2bf(fv.w);
            *(ushort4*)(dst + q * 4) = hv;
            *(float4*)(srcf + q * 4) = z4;   // zero for next step's atomics
          }
        }
      } else {
        uint4 z; z.x = z.y = z.z = z.w = 0u;
#pragma unroll
        for (int q = 0; q < 4; ++q) *(uint4*)(dst + q * 8) = z;
      }
    }
    STAGE_WT(Wt0, 256, seg * 128)
    __syncthreads();
    MFMA_K128_M16()
  }
  RELU_TO_ABUF1()
  INIT_ACC1(b1)
  __syncthreads();
  STAGE_WT(Wt1, 128, 0)
  __syncthreads();
  MFMA_K128_M16()
  RELU_TO_ABUF1()
  INIT_ACC1(b2)
  __syncthreads();
  STAGE_WT(Wt2, 128, 0)
  __syncthreads();
  MFMA_K128_M16()

  LN_STATS1(lmean, lrstd)
  float sv[8], ov[8];
#pragma unroll
  for (int nt = 0; nt < 8; ++nt) { sv[nt] = lns[nt * 16 + lr]; ov[nt] = lno[nt * 16 + lr]; }
#pragma unroll
  for (int i = 0; i < 4; ++i) {
    int row = rw + kg * 4 + i;
    int ng = n0 + row;
    if (ng < NN) {
#pragma unroll
      for (int nt = 0; nt < 8; ++nt) {
        float o = (acc[nt][i] - lmean[i]) * lrstd[i] * sv[nt] + ov[nt];
        size_t idx = (size_t)ng * LDIM + nt * 16 + lr;
        float nv = nodes_f[idx] + o;
        nodes_f[idx] = nv;
        nodes_bf[idx] = f2bf(nv);
      }
    }
  }
}

// ---- decoder: 128->128->128->3 (no LN) ----
__global__ __launch_bounds__(256, 2)
void k_dec_m(const ushort_t* __restrict__ nodes_bf,
             const ushort_t* __restrict__ Wt0, const float* __restrict__ b0,
             const ushort_t* __restrict__ Wt1, const float* __restrict__ b1,
             const float* __restrict__ W2f, const float* __restrict__ b2,
             float* __restrict__ out) {
  __shared__ ushort_t Abuf[128 * PADB];
  __shared__ ushort_t Wbuf[128 * PADB];
  const int t = threadIdx.x;
  const int lane = t & 63, wid = t >> 6;
  const int lr = lane & 15, kg = lane >> 4;
  const int rw = wid * 32;
  const int n0 = blockIdx.x * 128;

  {
    const int r = t >> 1, h = t & 1;
    const int ng = n0 + r;
    ushort_t* dst = &Abuf[r * PADB + h * 64];
    if (ng < NN) {
      const ushort_t* src = nodes_bf + (size_t)ng * LDIM + h * 64;
#pragma unroll
      for (int q = 0; q < 8; ++q)
        *(uint4*)(dst + q * 8) = *(const uint4*)(src + q * 8);
    } else {
      uint4 z; z.x = z.y = z.z = z.w = 0u;
#pragma unroll
      for (int q = 0; q < 8; ++q) *(uint4*)(dst + q * 8) = z;
    }
  }
  f32x4 acc[2][8];
  INIT_ACC(b0)
  STAGE_WT(Wt0, 128, 0)
  __syncthreads();
  MFMA_K128()
  __syncthreads();
  RELU_TO_ABUF()
  INIT_ACC(b1)
  STAGE_WT(Wt1, 128, 0)
  __syncthreads();
  MFMA_K128()
  __syncthreads();
  RELU_TO_ABUF()
  __syncthreads();

  if (t < 128) {
    const int ng = n0 + t;
    if (ng < NN) {
      float s0 = b2[0], s1 = b2[1], s2 = b2[2];
      for (int k = 0; k < 128; ++k) {
        float xv = bf2f(Abuf[t * PADB + k]);
        s0 = fmaf(xv, W2f[k * 3 + 0], s0);
        s1 = fmaf(xv, W2f[k * 3 + 1], s1);
        s2 = fmaf(xv, W2f[k * 3 + 2], s2);
      }
      out[(size_t)ng * 3 + 0] = s0;
      out[(size_t)ng * 3 + 1] = s1;
      out[(size_t)ng * 3 + 2] = s2;
    }
  }
}

extern "C" void kernel_launch(void* const* d_in, const int* in_sizes, int n_in,
                              void* d_out, int out_size, void* d_ws, size_t ws_size,
                              hipStream_t stream) {
  const float* vel_hist = (const float*)d_in[0];
  const float* vel_mag  = (const float*)d_in[1];
  const float* bnd      = (const float*)d_in[2];
  const float* force    = (const float*)d_in[3];
  const float* rel_disp = (const float*)d_in[4];
  const float* rel_dist = (const float*)d_in[5];
  const int*   senders   = (const int*)d_in[6];
  const int*   receivers = (const int*)d_in[7];
  const float* en_W0 = (const float*)d_in[8];  const float* en_b0 = (const float*)d_in[9];
  const float* en_W1 = (const float*)d_in[10]; const float* en_b1 = (const float*)d_in[11];
  const float* en_W2 = (const float*)d_in[12]; const float* en_b2 = (const float*)d_in[13];
  const float* ee_W0 = (const float*)d_in[14]; const float* ee_b0 = (const float*)d_in[15];
  const float* ee_W1 = (const float*)d_in[16]; const float* ee_b1 = (const float*)d_in[17];
  const float* ee_W2 = (const float*)d_in[18]; const float* ee_b2 = (const float*)d_in[19];
  const float* pe_W0 = (const float*)d_in[20]; const float* pe_b0 = (const float*)d_in[21];
  const float* pe_W1 = (const float*)d_in[22]; const float* pe_b1 = (const float*)d_in[23];
  const float* pe_W2 = (const float*)d_in[24]; const float* pe_b2 = (const float*)d_in[25];
  const float* pn_W0 = (const float*)d_in[26]; const float* pn_b0 = (const float*)d_in[27];
  const float* pn_W1 = (const float*)d_in[28]; const float* pn_b1 = (const float*)d_in[29];
  const float* pn_W2 = (const float*)d_in[30]; const float* pn_b2 = (const float*)d_in[31];
  const float* de_W0 = (const float*)d_in[32]; const float* de_b0 = (const float*)d_in[33];
  const float* de_W1 = (const float*)d_in[34]; const float* de_b1 = (const float*)d_in[35];
  const float* de_W2 = (const float*)d_in[36]; const float* de_b2 = (const float*)d_in[37];
  const float* en_s = (const float*)d_in[38]; const float* en_o = (const float*)d_in[39];
  const float* ee_s = (const float*)d_in[40]; const float* ee_o = (const float*)d_in[41];
  const float* pe_s = (const float*)d_in[42]; const float* pe_o = (const float*)d_in[43];
  const float* pn_s = (const float*)d_in[44]; const float* pn_o = (const float*)d_in[45];

  // ---- workspace layout ----
  float* nodes_f = (float*)d_ws;
  float* edges_f = nodes_f + (size_t)NN * LDIM;
  float* aggr    = edges_f + (size_t)NE * LDIM;
  ushort_t* nodes_bf = (ushort_t*)(aggr + (size_t)NN * LDIM);
  ushort_t* w = nodes_bf + (size_t)NN * LDIM;
  ushort_t* wEn0 = w; w += 128 * 32;
  ushort_t* wEn1 = w; w += 128 * 128;
  ushort_t* wEn2 = w; w += 128 * 128;
  ushort_t* wEe0 = w; w += 128 * 32;
  ushort_t* wEe1 = w; w += 128 * 128;
  ushort_t* wEe2 = w; w += 128 * 128;
  ushort_t* wPe0 = w; w += (size_t)NSTEP * 128 * 384;
  ushort_t* wPe1 = w; w += (size_t)NSTEP * 128 * 128;
  ushort_t* wPe2 = w; w += (size_t)NSTEP * 128 * 128;
  ushort_t* wPn0 = w; w += (size_t)NSTEP * 128 * 256;
  ushort_t* wPn1 = w; w += (size_t)NSTEP * 128 * 128;
  ushort_t* wPn2 = w; w += (size_t)NSTEP * 128 * 128;
  ushort_t* wDe0 = w; w += 128 * 128;
  ushort_t* wDe1 = w; w += 128 * 128;
  int* cnt       = (int*)w;
  int* row_start = cnt + NN;
  int* cursor    = row_start + NN + 1;
  int* esrc      = cursor + NN;
  int* sSend     = esrc + NE;
  int* sRecv     = sSend + NE;

  auto prep = [&](const float* src, ushort_t* dst, int Ks, int Kd, int N_, int st) {
    size_t total = (size_t)st * N_ * Kd;
    int blocks = (int)((total + 255) / 256);
    if (blocks > 1024) blocks = 1024;
    k_prep_w<<<blocks, 256, 0, stream>>>(src, dst, Ks, Kd, N_, st);
  };
  prep(en_W0, wEn0, 29, 32, 128, 1);
  prep(en_W1, wEn1, 128, 128, 128, 1);
  prep(en_W2, wEn2, 128, 128, 128, 1);
  prep(ee_W0, wEe0, 4, 32, 128, 1);
  prep(ee_W1, wEe1, 128, 128, 128, 1);
  prep(ee_W2, wEe2, 128, 128, 128, 1);
  prep(pe_W0, wPe0, 384, 384, 128, NSTEP);
  prep(pe_W1, wPe1, 128, 128, 128, NSTEP);
  prep(pe_W2, wPe2, 128, 128, 128, NSTEP);
  prep(pn_W0, wPn0, 256, 256, 128, NSTEP);
  prep(pn_W1, wPn1, 128, 128, 128, NSTEP);
  prep(pn_W2, wPn2, 128, 128, 128, NSTEP);
  prep(de_W0, wDe0, 128, 128, 128, 1);
  prep(de_W1, wDe1, 128, 128, 128, 1);

  // ---- counting sort by receiver ----
  hipMemsetAsync(cnt, 0, NN * sizeof(int), stream);
  hipMemsetAsync(cursor, 0, NN * sizeof(int), stream);
  k_hist<<<(NE + 255) / 256, 256, 0, stream>>>(receivers, cnt);
  k_scan<<<1, 256, 0, stream>>>(cnt, row_start);
  k_scatter<<<(NE + 255) / 256, 256, 0, stream>>>(senders, receivers, row_start,
                                                  cursor, esrc, sSend, sRecv);

  const int NB  = (NN + 127) / 128;   // 79  (encoders/decoder)
  const int NBn = (NN + 63) / 64;     // 157 (node processor)
  const int EB  = (NE + 127) / 128;   // 1563

  k_enc_node_m<<<NB, 256, 0, stream>>>(vel_hist, vel_mag, bnd, force,
      wEn0, en_b0, wEn1, en_b1, wEn2, en_b2, en_s, en_o, nodes_f, nodes_bf);
  k_enc_edge_m<<<EB, 256, 0, stream>>>(rel_disp, rel_dist, esrc,
      wEe0, ee_b0, wEe1, ee_b1, wEe2, ee_b2, ee_s, ee_o, edges_f);

  // zero aggr once; k_proc_node_m re-zeroes after each consume
  hipMemsetAsync(aggr, 0, (size_t)NN * LDIM * sizeof(float), stream);

  for (int s = 0; s < NSTEP; ++s) {
    k_proc_edge_m<<<EB, 512, 0, stream>>>(nodes_bf, edges_f, aggr, sSend, sRecv,
        wPe0 + (size_t)s * 128 * 384, pe_b0 + (size_t)s * LDIM,
        wPe1 + (size_t)s * 128 * 128, pe_b1 + (size_t)s * LDIM,
        wPe2 + (size_t)s * 128 * 128, pe_b2 + (size_t)s * LDIM,
        pe_s + (size_t)s * LDIM, pe_o + (size_t)s * LDIM);
    k_proc_node_m<<<NBn, 256, 0, stream>>>(nodes_f, nodes_bf, aggr,
        wPn0 + (size_t)s * 128 * 256, pn_b0 + (size_t)s * LDIM,
        wPn1 + (size_t)s * 128 * 128, pn_b1 + (size_t)s * LDIM,
        wPn2 + (size_t)s * 128 * 128, pn_b2 + (size_t)s * LDIM,
        pn_s + (size_t)s * LDIM, pn_o + (size_t)s * LDIM);
  }

  k_dec_m<<<NB, 256, 0, stream>>>(nodes_bf, wDe0, de_b0, wDe1, de_b1, de_W2, de_b2,
                                  (float*)d_out);
}